// Round 6
// baseline (227.407 us; speedup 1.0000x reference)
//
#include <hip/hip_runtime.h>
#include <stdint.h>

#define D 128
#define E_EDGES 50000
#define S_NEG 16
#define N_A 100000
#define N_B 50000
#define ES (E_EDGES * S_NEG)

#define HW 12500      // LDS hist words (50000 bins as packed bytes)
#define ACH 38        // A-source chunks of 25000 items (2+2+2+32)
#define BCH 34        // B-source chunks of 25000 items (2+32)
#define GA 1024       // scan blocks for A table (8192 groups)
#define GB 512        // scan blocks for B table (4096 groups)
#define RPG 13        // rows per group (8192*13 >= 100000, 4096*13 >= 50000)
#define RA 32         // stage-1-reduced A partials (32*32 = 1024 = GA)
#define RB 16         // stage-1-reduced B partials (16*32 = 512 = GB)

__device__ inline float dot4(float4 a, float4 b) {
    return a.x * b.x + a.y * b.y + a.z * b.z + a.w * b.w;
}
#define RED32(p) { p += __shfl_xor(p, 1); p += __shfl_xor(p, 2); p += __shfl_xor(p, 4); \
                   p += __shfl_xor(p, 8); p += __shfl_xor(p, 16); }

// ---------------------------------------------------------------------------
// ws layout (4-byte words):
//   u32    partA[76 * HW]   byte-hist slabs, slab = chunk*2 + half
//   u32    partB[34 * HW]
//   float4 cwA[N_A]   per-row float counts {pos0, nh0, nh1, nt0}
//   float2 cwB[N_B]   per-row float counts {pos1, nt1}
//   f32 psumA[GA*512], psumB[GB*256]     scan1 per-block partials
//   f32 psumA2[RA*512], psumB2[RB*256]   stage-1 reduced
//   f32 cvec[6*D]
//   f32 PA[5*N_A]  (SoA planes: pos0,pos1,nh0,nh1,nt0);  f32 PB[N_B]
// ---------------------------------------------------------------------------

__global__ void k_hist(const int* __restrict__ ei0, const int* __restrict__ ei1,
                       const int* __restrict__ nh0, const int* __restrict__ nh1,
                       const int* __restrict__ nt0, const int* __restrict__ nt1,
                       uint32_t* __restrict__ partA, uint32_t* __restrict__ partB) {
    __shared__ uint32_t h[HW];
    const int tid = threadIdx.x;   // 512
    for (int w = tid; w < HW; w += 512) h[w] = 0;
    __syncthreads();

    const int b = blockIdx.x;
    if (b < 2 * ACH) {             // ---- A-table sources (two halves per chunk)
        const int c = b >> 1, hh = b & 1;
        const unsigned lo = hh * 50000u;
        uint32_t* dst = partA + (size_t)b * HW;
        if (c >= 2 && c < 6) {
            // nh columns (stride 16): c 2-3 = nh0, 4-5 = nh1
            const int* src = (c < 4) ? nh0 : nh1;
            const long long base = (long long)(c & 1) * 25000 * S_NEG;
            for (int i = tid; i < 25000; i += 512) {
                const unsigned r = (unsigned)src[base + (long long)i * S_NEG] - lo;
                if (r < 50000u) atomicAdd(&h[r >> 2], 1u << ((r & 3u) * 8u));
            }
        } else {
            // flat int4 sources: c 0-1 = pos0 tails (ei0[E..2E)), 6-37 = nt0
            const int* srcp = (c < 2) ? (ei0 + E_EDGES + c * 25000)
                                      : (nt0 + (c - 6) * 25000);
            const int4* src4 = reinterpret_cast<const int4*>(srcp);
            for (int i = tid; i < 6250; i += 512) {
                const int4 v = src4[i];
                unsigned r;
                r = (unsigned)v.x - lo; if (r < 50000u) atomicAdd(&h[r >> 2], 1u << ((r & 3u) * 8u));
                r = (unsigned)v.y - lo; if (r < 50000u) atomicAdd(&h[r >> 2], 1u << ((r & 3u) * 8u));
                r = (unsigned)v.z - lo; if (r < 50000u) atomicAdd(&h[r >> 2], 1u << ((r & 3u) * 8u));
                r = (unsigned)v.w - lo; if (r < 50000u) atomicAdd(&h[r >> 2], 1u << ((r & 3u) * 8u));
            }
        }
        __syncthreads();
        for (int w = tid; w < HW; w += 512) dst[w] = h[w];
    } else {                       // ---- B-table sources (full 50k range, one pass)
        const int c = b - 2 * ACH;
        uint32_t* dst = partB + (size_t)c * HW;
        const int* srcp = (c < 2) ? (ei1 + E_EDGES + c * 25000)
                                  : (nt1 + (c - 2) * 25000);
        const int4* src4 = reinterpret_cast<const int4*>(srcp);
        for (int i = tid; i < 6250; i += 512) {
            const int4 v = src4[i];
            unsigned r;
            r = (unsigned)v.x; if (r < 50000u) atomicAdd(&h[r >> 2], 1u << ((r & 3u) * 8u));
            r = (unsigned)v.y; if (r < 50000u) atomicAdd(&h[r >> 2], 1u << ((r & 3u) * 8u));
            r = (unsigned)v.z; if (r < 50000u) atomicAdd(&h[r >> 2], 1u << ((r & 3u) * 8u));
            r = (unsigned)v.w; if (r < 50000u) atomicAdd(&h[r >> 2], 1u << ((r & 3u) * 8u));
        }
        __syncthreads();
        for (int w = tid; w < HW; w += 512) dst[w] = h[w];
    }
}

// thread-per-bin: sum byte partials -> FLOAT counts (FMA-ready in scan1).
__global__ void k_reduceC(const uint32_t* __restrict__ partA,
                          const uint32_t* __restrict__ partB,
                          float4* __restrict__ cwA, float2* __restrict__ cwB) {
    const int t = blockIdx.x * 256 + threadIdx.x;
    if (t < N_A) {
        const int n = t;
        const int hh = (n >= 50000);
        const int w = (n - hh * 50000) >> 2;
        const int sh = (n & 3) * 8;
        const uint32_t* p = partA + (size_t)hh * HW + w;   // slab (c*2+hh)
        unsigned s0 = 0, s1 = 0, s2 = 0, s3 = 0;
#pragma unroll
        for (int c = 0; c < 2; ++c)  s0 += (p[(size_t)(c * 2) * HW] >> sh) & 255u;
#pragma unroll
        for (int c = 2; c < 4; ++c)  s1 += (p[(size_t)(c * 2) * HW] >> sh) & 255u;
#pragma unroll
        for (int c = 4; c < 6; ++c)  s2 += (p[(size_t)(c * 2) * HW] >> sh) & 255u;
#pragma unroll 8
        for (int c = 6; c < 38; ++c) s3 += (p[(size_t)(c * 2) * HW] >> sh) & 255u;
        cwA[n] = make_float4((float)s0, (float)s1, (float)s2, (float)s3);
    } else if (t < N_A + N_B) {
        const int n = t - N_A;
        const int w = n >> 2;
        const int sh = (n & 3) * 8;
        const uint32_t* p = partB + w;
        unsigned s0 = 0, s1 = 0;
#pragma unroll
        for (int c = 0; c < 2; ++c)  s0 += (p[(size_t)c * HW] >> sh) & 255u;
#pragma unroll 8
        for (int c = 2; c < 34; ++c) s1 += (p[(size_t)c * HW] >> sh) & 255u;
        cwB[n] = make_float2((float)s0, (float)s1);
    }
}

// Weighted table scan, 4-row unroll (8 independent loads in flight per iter).
__global__ void k_scan1(const float* __restrict__ embA, const float* __restrict__ embB,
                        const float4* __restrict__ cwA, const float2* __restrict__ cwB,
                        float* __restrict__ psumA, float* __restrict__ psumB) {
    __shared__ float sds[4 * D];
    const int tid = threadIdx.x;
    const int l = tid & 31;
    const int grp = tid >> 5;

    for (int j = tid; j < 4 * D; j += 256) sds[j] = 0.f;
    __syncthreads();

    if ((int)blockIdx.x < GA) {
        const int gid = blockIdx.x * 8 + grp;
        int r = gid * RPG;
        const int end = min(r + RPG, N_A);
        float acc[16];
#pragma unroll
        for (int k = 0; k < 16; ++k) acc[k] = 0.f;
        const float* base = embA + 4 * l;
        for (; r + 4 <= end; r += 4) {
            float4 w[4], x[4];
#pragma unroll
            for (int u = 0; u < 4; ++u) w[u] = cwA[r + u];
#pragma unroll
            for (int u = 0; u < 4; ++u)
                x[u] = *reinterpret_cast<const float4*>(base + (size_t)(r + u) * D);
#pragma unroll
            for (int u = 0; u < 4; ++u) {
                acc[0]  += w[u].x * x[u].x; acc[1]  += w[u].x * x[u].y;
                acc[2]  += w[u].x * x[u].z; acc[3]  += w[u].x * x[u].w;
                acc[4]  += w[u].y * x[u].x; acc[5]  += w[u].y * x[u].y;
                acc[6]  += w[u].y * x[u].z; acc[7]  += w[u].y * x[u].w;
                acc[8]  += w[u].z * x[u].x; acc[9]  += w[u].z * x[u].y;
                acc[10] += w[u].z * x[u].z; acc[11] += w[u].z * x[u].w;
                acc[12] += w[u].w * x[u].x; acc[13] += w[u].w * x[u].y;
                acc[14] += w[u].w * x[u].z; acc[15] += w[u].w * x[u].w;
            }
        }
        for (; r < end; ++r) {
            const float4 w0 = cwA[r];
            const float4 x0 = *reinterpret_cast<const float4*>(base + (size_t)r * D);
            acc[0]  += w0.x * x0.x; acc[1]  += w0.x * x0.y; acc[2]  += w0.x * x0.z; acc[3]  += w0.x * x0.w;
            acc[4]  += w0.y * x0.x; acc[5]  += w0.y * x0.y; acc[6]  += w0.y * x0.z; acc[7]  += w0.y * x0.w;
            acc[8]  += w0.z * x0.x; acc[9]  += w0.z * x0.y; acc[10] += w0.z * x0.z; acc[11] += w0.z * x0.w;
            acc[12] += w0.w * x0.x; acc[13] += w0.w * x0.y; acc[14] += w0.w * x0.z; acc[15] += w0.w * x0.w;
        }
#pragma unroll
        for (int p = 0; p < 4; ++p)
#pragma unroll
            for (int k = 0; k < 4; ++k)
                atomicAdd(&sds[p * D + 4 * l + k], acc[p * 4 + k]);
        __syncthreads();
        for (int j = tid; j < 4 * D; j += 256)
            psumA[(size_t)blockIdx.x * 512 + j] = sds[j];
    } else {
        const int gid = (blockIdx.x - GA) * 8 + grp;
        int r = gid * RPG;
        const int end = min(r + RPG, N_B);
        float acc[8];
#pragma unroll
        for (int k = 0; k < 8; ++k) acc[k] = 0.f;
        const float* base = embB + 4 * l;
        for (; r + 4 <= end; r += 4) {
            float2 w[4]; float4 x[4];
#pragma unroll
            for (int u = 0; u < 4; ++u) w[u] = cwB[r + u];
#pragma unroll
            for (int u = 0; u < 4; ++u)
                x[u] = *reinterpret_cast<const float4*>(base + (size_t)(r + u) * D);
#pragma unroll
            for (int u = 0; u < 4; ++u) {
                acc[0] += w[u].x * x[u].x; acc[1] += w[u].x * x[u].y;
                acc[2] += w[u].x * x[u].z; acc[3] += w[u].x * x[u].w;
                acc[4] += w[u].y * x[u].x; acc[5] += w[u].y * x[u].y;
                acc[6] += w[u].y * x[u].z; acc[7] += w[u].y * x[u].w;
            }
        }
        for (; r < end; ++r) {
            const float2 w0 = cwB[r];
            const float4 x0 = *reinterpret_cast<const float4*>(base + (size_t)r * D);
            acc[0] += w0.x * x0.x; acc[1] += w0.x * x0.y; acc[2] += w0.x * x0.z; acc[3] += w0.x * x0.w;
            acc[4] += w0.y * x0.x; acc[5] += w0.y * x0.y; acc[6] += w0.y * x0.z; acc[7] += w0.y * x0.w;
        }
#pragma unroll
        for (int p = 0; p < 2; ++p)
#pragma unroll
            for (int k = 0; k < 4; ++k)
                atomicAdd(&sds[p * D + 4 * l + k], acc[p * 4 + k]);
        __syncthreads();
        for (int j = tid; j < 2 * D; j += 256)
            psumB[(size_t)(blockIdx.x - GA) * 256 + j] = sds[j];
    }
}

// Stage-1 tree reduce: 32 psum rows per block, coalesced.
__global__ void k_red1(const float* __restrict__ psumA, const float* __restrict__ psumB,
                       float* __restrict__ psumA2, float* __restrict__ psumB2) {
    const int b = blockIdx.x, t = threadIdx.x;
    if (b < RA) {
        const float* p = psumA + (size_t)b * 32 * 512;
        float s0 = 0.f, s1 = 0.f;
#pragma unroll 8
        for (int r = 0; r < 32; ++r) { s0 += p[r * 512 + t]; s1 += p[r * 512 + 256 + t]; }
        psumA2[(size_t)b * 512 + t] = s0;
        psumA2[(size_t)b * 512 + 256 + t] = s1;
    } else {
        const int bi = b - RA;
        const float* p = psumB + (size_t)bi * 32 * 256;
        float s = 0.f;
#pragma unroll 8
        for (int r = 0; r < 32; ++r) s += p[r * 256 + t];
        psumB2[(size_t)bi * 256 + t] = s;
    }
}

// Final reduce -> s_j; c_j = scale_j * K_{j%2} @ s_j with K staged in LDS.
__global__ void k_cvec2(const float* __restrict__ rel,
                        const float* __restrict__ psumA2, const float* __restrict__ psumB2,
                        float* __restrict__ cvec) {
    const int j = blockIdx.x;        // 0..5: pos0,pos1,nh0,nh1,nt0,nt1
    const int tid = threadIdx.x;     // 256
    __shared__ float Kds[D * 129];
    __shared__ float red[256];
    __shared__ float sv[D];
    const float* Kp = rel + (size_t)(j & 1) * D * D;

    for (int e = tid; e < D * D / 4; e += 256) {
        const int row = e >> 5, col = (e & 31) * 4;
        const float4 v = *reinterpret_cast<const float4*>(Kp + (size_t)row * D + col);
        float* dst = Kds + row * 129 + col;
        dst[0] = v.x; dst[1] = v.y; dst[2] = v.z; dst[3] = v.w;
    }

    const int g = tid >> 7, i = tid & 127;
    float s = 0.f;
    if (j == 1 || j == 5) {
        const int plane = (j == 1) ? 0 : 1;
        for (int b = g; b < RB; b += 2) s += psumB2[(size_t)b * 256 + plane * D + i];
    } else {
        const int plane = (j == 0) ? 0 : (j - 1);
        for (int b = g; b < RA; b += 2) s += psumA2[(size_t)b * 512 + plane * D + i];
    }
    red[tid] = s;
    __syncthreads();
    if (tid < 128) sv[i] = red[i] + red[128 + i];
    __syncthreads();

    if (tid < 128) {
        const float scale = (j == 2 || j == 3) ? (float)S_NEG : 1.0f;
        float acc = 0.f;
#pragma unroll
        for (int k = 0; k < D; k += 4)
            acc += Kds[i * 129 + k] * sv[k] + Kds[i * 129 + k + 1] * sv[k + 1]
                 + Kds[i * 129 + k + 2] * sv[k + 2] + Kds[i * 129 + k + 3] * sv[k + 3];
        cvec[j * D + i] = acc * scale;
    }
}

// SoA: PA[p*N_A + n] = emb_A[n].c_p (p=0..4);  PB[n] = emb_B[n].c_5
__global__ void k_scan2(const float* __restrict__ embA, const float* __restrict__ embB,
                        const float* __restrict__ cvec, float* __restrict__ PA,
                        float* __restrict__ PB) {
    __shared__ float sc[5 * D];
    const int tid = threadIdx.x;
    const int l = tid & 31;
    const int grp = tid >> 5;

    if ((int)blockIdx.x < GA) {
        for (int j = tid; j < 5 * D; j += 256) sc[j] = cvec[j];  // c0..c4
        __syncthreads();
        float4 cf[5];
#pragma unroll
        for (int p = 0; p < 5; ++p)
            cf[p] = *reinterpret_cast<const float4*>(sc + p * D + 4 * l);
        const int gid = blockIdx.x * 8 + grp;
        int r = gid * RPG;
        const int end = min(r + RPG, N_A);
        const float* base = embA + 4 * l;
        for (; r + 4 <= end; r += 4) {
            float4 x[4];
#pragma unroll
            for (int u = 0; u < 4; ++u)
                x[u] = *reinterpret_cast<const float4*>(base + (size_t)(r + u) * D);
            float p_[4][5];
#pragma unroll
            for (int u = 0; u < 4; ++u)
#pragma unroll
                for (int p = 0; p < 5; ++p) p_[u][p] = dot4(x[u], cf[p]);
#pragma unroll
            for (int u = 0; u < 4; ++u)
#pragma unroll
                for (int p = 0; p < 5; ++p) RED32(p_[u][p]);
            if (l < 4) {
#pragma unroll
                for (int p = 0; p < 5; ++p) {
                    float v = p_[0][p];
                    v = (l == 1) ? p_[1][p] : v;
                    v = (l == 2) ? p_[2][p] : v;
                    v = (l == 3) ? p_[3][p] : v;
                    PA[(size_t)p * N_A + r + l] = v;   // 16B coalesced per plane
                }
            }
        }
        for (; r < end; ++r) {
            const float4 x0 = *reinterpret_cast<const float4*>(base + (size_t)r * D);
            float q[5];
#pragma unroll
            for (int p = 0; p < 5; ++p) { q[p] = dot4(x0, cf[p]); RED32(q[p]); }
            if (l == 0) {
#pragma unroll
                for (int p = 0; p < 5; ++p) PA[(size_t)p * N_A + r] = q[p];
            }
        }
    } else {
        for (int j = tid; j < D; j += 256) sc[j] = cvec[5 * D + j];  // c5
        __syncthreads();
        const float4 cf = *reinterpret_cast<const float4*>(sc + 4 * l);
        const int gid = (blockIdx.x - GA) * 8 + grp;
        int r = gid * RPG;
        const int end = min(r + RPG, N_B);
        const float* base = embB + 4 * l;
        for (; r + 4 <= end; r += 4) {
            float4 x[4];
#pragma unroll
            for (int u = 0; u < 4; ++u)
                x[u] = *reinterpret_cast<const float4*>(base + (size_t)(r + u) * D);
            float p_[4];
#pragma unroll
            for (int u = 0; u < 4; ++u) { p_[u] = dot4(x[u], cf); RED32(p_[u]); }
            if (l < 4)
                PB[r + l] = (l == 1) ? p_[1] : (l == 2) ? p_[2] : (l == 3) ? p_[3] : p_[0];
        }
        for (; r < end; ++r) {
            const float4 x0 = *reinterpret_cast<const float4*>(base + (size_t)r * D);
            float q = dot4(x0, cf); RED32(q);
            if (l == 0) PB[r] = q;
        }
    }
}

// Vectorized scatter from SoA planes: int4 index loads, float4 stores.
__global__ void k_scatter(const int* __restrict__ ei0, const int* __restrict__ ei1,
                          const int* __restrict__ nh0, const int* __restrict__ nh1,
                          const int* __restrict__ nt0, const int* __restrict__ nt1,
                          const float* __restrict__ PA, const float* __restrict__ PB,
                          float* __restrict__ out) {
    const int total4 = (2 * E_EDGES + 4 * ES) / 4;  // 825000
    const float* P0 = PA;
    const float* P1 = PA + (size_t)N_A;
    const float* P2 = PA + (size_t)2 * N_A;
    const float* P3 = PA + (size_t)3 * N_A;
    const float* P4 = PA + (size_t)4 * N_A;
    for (int t = blockIdx.x * blockDim.x + threadIdx.x; t < total4;
         t += gridDim.x * blockDim.x) {
        const int e = t * 4;
        float4 v;
        if (e < E_EDGES) {
            const int4 i4 = *reinterpret_cast<const int4*>(ei0 + e);
            v = make_float4(P0[i4.x], P0[i4.y], P0[i4.z], P0[i4.w]);
        } else if (e < 2 * E_EDGES) {
            const int4 i4 = *reinterpret_cast<const int4*>(ei1 + (e - E_EDGES));
            v = make_float4(P1[i4.x], P1[i4.y], P1[i4.z], P1[i4.w]);
        } else if (e < 2 * E_EDGES + ES) {
            const int4 i4 = *reinterpret_cast<const int4*>(nh0 + (e - 2 * E_EDGES));
            v = make_float4(P2[i4.x], P2[i4.y], P2[i4.z], P2[i4.w]);
        } else if (e < 2 * E_EDGES + 2 * ES) {
            const int4 i4 = *reinterpret_cast<const int4*>(nh1 + (e - 2 * E_EDGES - ES));
            v = make_float4(P3[i4.x], P3[i4.y], P3[i4.z], P3[i4.w]);
        } else if (e < 2 * E_EDGES + 3 * ES) {
            const int i = e - 2 * E_EDGES - 2 * ES;
            const float s = P4[nt0[(i >> 4) << 4]];
            v = make_float4(s, s, s, s);
        } else {
            const int i = e - 2 * E_EDGES - 3 * ES;
            const float s = PB[nt1[(i >> 4) << 4]];
            v = make_float4(s, s, s, s);
        }
        *reinterpret_cast<float4*>(out + e) = v;
    }
}

extern "C" void kernel_launch(void* const* d_in, const int* in_sizes, int n_in,
                              void* d_out, int out_size, void* d_ws, size_t ws_size,
                              hipStream_t stream) {
    const float* embA = (const float*)d_in[0];
    const float* embB = (const float*)d_in[1];
    const float* rel  = (const float*)d_in[2];
    const int* ei0 = (const int*)d_in[3];
    const int* ei1 = (const int*)d_in[4];
    const int* nh0 = (const int*)d_in[5];
    const int* nh1 = (const int*)d_in[6];
    const int* nt0 = (const int*)d_in[7];
    const int* nt1 = (const int*)d_in[8];
    float* out = (float*)d_out;

    uint32_t* partA = (uint32_t*)d_ws;                        // 76*HW
    uint32_t* partB = partA + (size_t)2 * ACH * HW;           // 34*HW
    float4* cwA = (float4*)(partB + (size_t)BCH * HW);        // N_A float4
    float2* cwB = (float2*)(cwA + N_A);                       // N_B float2
    float* psumA = (float*)(cwB + N_B);                       // GA*512
    float* psumB = psumA + (size_t)GA * 512;                  // GB*256
    float* psumA2 = psumB + (size_t)GB * 256;                 // RA*512
    float* psumB2 = psumA2 + (size_t)RA * 512;                // RB*256
    float* cvec  = psumB2 + (size_t)RB * 256;                 // 6*D
    float* PA    = cvec + 6 * D;                              // 5*N_A (SoA)
    float* PB    = PA + (size_t)5 * N_A;                      // N_B

    k_hist<<<2 * ACH + BCH, 512, 0, stream>>>(ei0, ei1, nh0, nh1, nt0, nt1, partA, partB);
    k_reduceC<<<(N_A + N_B + 255) / 256, 256, 0, stream>>>(partA, partB, cwA, cwB);
    k_scan1<<<GA + GB, 256, 0, stream>>>(embA, embB, cwA, cwB, psumA, psumB);
    k_red1<<<RA + RB, 256, 0, stream>>>(psumA, psumB, psumA2, psumB2);
    k_cvec2<<<6, 256, 0, stream>>>(rel, psumA2, psumB2, cvec);
    k_scan2<<<GA + GB, 256, 0, stream>>>(embA, embB, cvec, PA, PB);
    k_scatter<<<2048, 256, 0, stream>>>(ei0, ei1, nh0, nh1, nt0, nt1, PA, PB, out);
}

// Round 7
// 191.357 us; speedup vs baseline: 1.1884x; 1.1884x over previous
//
#include <hip/hip_runtime.h>
#include <stdint.h>

#define D 128
#define E_EDGES 50000
#define S_NEG 16
#define N_A 100000
#define N_B 50000
#define ES (E_EDGES * S_NEG)

#define HW 12500      // LDS hist words (50000 bins as packed bytes)
#define ACH 38        // A-source chunks of 25000 items (2+2+2+32)
#define BCH 34        // B-source chunks of 25000 items (2+32)

#define GA1 500       // scan1 A blocks: 4000 groups * 25 rows = 100000 exactly
#define GB1 250       // scan1 B blocks: 2000 groups * 25 rows = 50000 exactly
#define RPG 25
#define RA2 20        // red1 A blocks (20 * 25 = 500 psum rows)
#define RB2 10        // red1 B blocks (10 * 25 = 250 psum rows)
#define GA2 391       // scan2 A blocks (391 * 256 >= 100000), lane-per-row
#define GB2 196       // scan2 B blocks (196 * 256 >= 50000)

__device__ inline float dot4(float4 a, float4 b) {
    return a.x * b.x + a.y * b.y + a.z * b.z + a.w * b.w;
}
__device__ inline void fma16(float* acc, const float4 w, const float4 x) {
    acc[0]  += w.x * x.x; acc[1]  += w.x * x.y; acc[2]  += w.x * x.z; acc[3]  += w.x * x.w;
    acc[4]  += w.y * x.x; acc[5]  += w.y * x.y; acc[6]  += w.y * x.z; acc[7]  += w.y * x.w;
    acc[8]  += w.z * x.x; acc[9]  += w.z * x.y; acc[10] += w.z * x.z; acc[11] += w.z * x.w;
    acc[12] += w.w * x.x; acc[13] += w.w * x.y; acc[14] += w.w * x.z; acc[15] += w.w * x.w;
}
__device__ inline void fma8(float* acc, const float2 w, const float4 x) {
    acc[0] += w.x * x.x; acc[1] += w.x * x.y; acc[2] += w.x * x.z; acc[3] += w.x * x.w;
    acc[4] += w.y * x.x; acc[5] += w.y * x.y; acc[6] += w.y * x.z; acc[7] += w.y * x.w;
}

// ---------------------------------------------------------------------------
// ws layout (4-byte words):
//   u32    partA[76*HW], partB[34*HW]     byte-hist slabs (slab = chunk*2+half / chunk)
//   float4 cwA[N_A]; float2 cwB[N_B]      per-row float counts
//   f32 psumA[GA1*512], psumB[GB1*256]    scan1 per-block partials [plane][128]
//   f32 psumA2[RA2*512], psumB2[RB2*256]  stage-1 reduced
//   f32 cvec[6*D]
//   f32 PA[5*N_A] (SoA planes), PB[N_B]
// ---------------------------------------------------------------------------

__global__ void k_hist(const int* __restrict__ ei0, const int* __restrict__ ei1,
                       const int* __restrict__ nh0, const int* __restrict__ nh1,
                       const int* __restrict__ nt0, const int* __restrict__ nt1,
                       uint32_t* __restrict__ partA, uint32_t* __restrict__ partB) {
    __shared__ uint32_t h[HW];
    const int tid = threadIdx.x;   // 512
    for (int w = tid; w < HW; w += 512) h[w] = 0;
    __syncthreads();

    const int b = blockIdx.x;
    if (b < 2 * ACH) {             // A-table sources (two halves per chunk)
        const int c = b >> 1, hh = b & 1;
        const unsigned lo = hh * 50000u;
        uint32_t* dst = partA + (size_t)b * HW;
        if (c >= 2 && c < 6) {     // nh columns (stride 16): c 2-3 = nh0, 4-5 = nh1
            const int* src = (c < 4) ? nh0 : nh1;
            const long long base = (long long)(c & 1) * 25000 * S_NEG;
            for (int i = tid; i < 25000; i += 512) {
                const unsigned r = (unsigned)src[base + (long long)i * S_NEG] - lo;
                if (r < 50000u) atomicAdd(&h[r >> 2], 1u << ((r & 3u) * 8u));
            }
        } else {                   // flat int4: c 0-1 = ei0 tails, 6-37 = nt0
            const int* srcp = (c < 2) ? (ei0 + E_EDGES + c * 25000)
                                      : (nt0 + (c - 6) * 25000);
            const int4* src4 = reinterpret_cast<const int4*>(srcp);
            for (int i = tid; i < 6250; i += 512) {
                const int4 v = src4[i];
                unsigned r;
                r = (unsigned)v.x - lo; if (r < 50000u) atomicAdd(&h[r >> 2], 1u << ((r & 3u) * 8u));
                r = (unsigned)v.y - lo; if (r < 50000u) atomicAdd(&h[r >> 2], 1u << ((r & 3u) * 8u));
                r = (unsigned)v.z - lo; if (r < 50000u) atomicAdd(&h[r >> 2], 1u << ((r & 3u) * 8u));
                r = (unsigned)v.w - lo; if (r < 50000u) atomicAdd(&h[r >> 2], 1u << ((r & 3u) * 8u));
            }
        }
        __syncthreads();
        for (int w = tid; w < HW; w += 512) dst[w] = h[w];
    } else {                       // B-table sources
        const int c = b - 2 * ACH;
        uint32_t* dst = partB + (size_t)c * HW;
        const int* srcp = (c < 2) ? (ei1 + E_EDGES + c * 25000)
                                  : (nt1 + (c - 2) * 25000);
        const int4* src4 = reinterpret_cast<const int4*>(srcp);
        for (int i = tid; i < 6250; i += 512) {
            const int4 v = src4[i];
            unsigned r;
            r = (unsigned)v.x; if (r < 50000u) atomicAdd(&h[r >> 2], 1u << ((r & 3u) * 8u));
            r = (unsigned)v.y; if (r < 50000u) atomicAdd(&h[r >> 2], 1u << ((r & 3u) * 8u));
            r = (unsigned)v.z; if (r < 50000u) atomicAdd(&h[r >> 2], 1u << ((r & 3u) * 8u));
            r = (unsigned)v.w; if (r < 50000u) atomicAdd(&h[r >> 2], 1u << ((r & 3u) * 8u));
        }
        __syncthreads();
        for (int w = tid; w < HW; w += 512) dst[w] = h[w];
    }
}

__global__ void k_reduceC(const uint32_t* __restrict__ partA,
                          const uint32_t* __restrict__ partB,
                          float4* __restrict__ cwA, float2* __restrict__ cwB) {
    const int t = blockIdx.x * 256 + threadIdx.x;
    if (t < N_A) {
        const int n = t;
        const int hh = (n >= 50000);
        const int w = (n - hh * 50000) >> 2;
        const int sh = (n & 3) * 8;
        const uint32_t* p = partA + (size_t)hh * HW + w;
        unsigned s0 = 0, s1 = 0, s2 = 0, s3 = 0;
#pragma unroll
        for (int c = 0; c < 2; ++c)  s0 += (p[(size_t)(c * 2) * HW] >> sh) & 255u;
#pragma unroll
        for (int c = 2; c < 4; ++c)  s1 += (p[(size_t)(c * 2) * HW] >> sh) & 255u;
#pragma unroll
        for (int c = 4; c < 6; ++c)  s2 += (p[(size_t)(c * 2) * HW] >> sh) & 255u;
#pragma unroll 8
        for (int c = 6; c < 38; ++c) s3 += (p[(size_t)(c * 2) * HW] >> sh) & 255u;
        cwA[n] = make_float4((float)s0, (float)s1, (float)s2, (float)s3);
    } else if (t < N_A + N_B) {
        const int n = t - N_A;
        const int w = n >> 2;
        const int sh = (n & 3) * 8;
        const uint32_t* p = partB + w;
        unsigned s0 = 0, s1 = 0;
#pragma unroll
        for (int c = 0; c < 2; ++c)  s0 += (p[(size_t)c * HW] >> sh) & 255u;
#pragma unroll 8
        for (int c = 2; c < 34; ++c) s1 += (p[(size_t)c * HW] >> sh) & 255u;
        cwB[n] = make_float2((float)s0, (float)s1);
    }
}

// Weighted table scan, explicit 5-row double-buffered pipeline, exact geometry.
__global__ void __launch_bounds__(256, 4)
k_scan1(const float* __restrict__ embA, const float* __restrict__ embB,
        const float4* __restrict__ cwA, const float2* __restrict__ cwB,
        float* __restrict__ psumA, float* __restrict__ psumB) {
    __shared__ float sds[4 * 512];
    const int tid = threadIdx.x;
    const int l = tid & 31;
    const int grp = tid >> 5;      // 0..7
    const int wid = tid >> 6;      // 0..3

    if ((int)blockIdx.x < GA1) {
        const int r0 = (blockIdx.x * 8 + grp) * RPG;
        const float* base = embA + 4 * l;
        float acc[16];
#pragma unroll
        for (int k = 0; k < 16; ++k) acc[k] = 0.f;
        float4 wc[5], xc[5];
#pragma unroll
        for (int u = 0; u < 5; ++u) {
            wc[u] = cwA[r0 + u];
            xc[u] = *reinterpret_cast<const float4*>(base + (size_t)(r0 + u) * D);
        }
#pragma unroll
        for (int b = 0; b < 5; ++b) {
            float4 wn[5], xn[5];
            if (b < 4) {
#pragma unroll
                for (int u = 0; u < 5; ++u) {
                    const int rr = r0 + (b + 1) * 5 + u;
                    wn[u] = cwA[rr];
                    xn[u] = *reinterpret_cast<const float4*>(base + (size_t)rr * D);
                }
            }
#pragma unroll
            for (int u = 0; u < 5; ++u) fma16(acc, wc[u], xc[u]);
            if (b < 4) {
#pragma unroll
                for (int u = 0; u < 5; ++u) { wc[u] = wn[u]; xc[u] = xn[u]; }
            }
        }
        // fold the wave's two 32-lane groups, then plain LDS stores
#pragma unroll
        for (int k = 0; k < 16; ++k) acc[k] += __shfl_xor(acc[k], 32);
        if ((tid & 32) == 0) {
            float* w0 = sds + wid * 512;
#pragma unroll
            for (int p = 0; p < 4; ++p)
                *reinterpret_cast<float4*>(w0 + p * 128 + 4 * l) =
                    make_float4(acc[4 * p], acc[4 * p + 1], acc[4 * p + 2], acc[4 * p + 3]);
        }
        __syncthreads();
        for (int j = tid; j < 512; j += 256)
            psumA[(size_t)blockIdx.x * 512 + j] =
                sds[j] + sds[512 + j] + sds[1024 + j] + sds[1536 + j];
    } else {
        const int r0 = ((blockIdx.x - GA1) * 8 + grp) * RPG;
        const float* base = embB + 4 * l;
        float acc[8];
#pragma unroll
        for (int k = 0; k < 8; ++k) acc[k] = 0.f;
        float2 wc[5]; float4 xc[5];
#pragma unroll
        for (int u = 0; u < 5; ++u) {
            wc[u] = cwB[r0 + u];
            xc[u] = *reinterpret_cast<const float4*>(base + (size_t)(r0 + u) * D);
        }
#pragma unroll
        for (int b = 0; b < 5; ++b) {
            float2 wn[5]; float4 xn[5];
            if (b < 4) {
#pragma unroll
                for (int u = 0; u < 5; ++u) {
                    const int rr = r0 + (b + 1) * 5 + u;
                    wn[u] = cwB[rr];
                    xn[u] = *reinterpret_cast<const float4*>(base + (size_t)rr * D);
                }
            }
#pragma unroll
            for (int u = 0; u < 5; ++u) fma8(acc, wc[u], xc[u]);
            if (b < 4) {
#pragma unroll
                for (int u = 0; u < 5; ++u) { wc[u] = wn[u]; xc[u] = xn[u]; }
            }
        }
#pragma unroll
        for (int k = 0; k < 8; ++k) acc[k] += __shfl_xor(acc[k], 32);
        if ((tid & 32) == 0) {
            float* w0 = sds + wid * 256;
#pragma unroll
            for (int p = 0; p < 2; ++p)
                *reinterpret_cast<float4*>(w0 + p * 128 + 4 * l) =
                    make_float4(acc[4 * p], acc[4 * p + 1], acc[4 * p + 2], acc[4 * p + 3]);
        }
        __syncthreads();
        for (int j = tid; j < 256; j += 256)
            psumB[(size_t)(blockIdx.x - GA1) * 256 + j] =
                sds[j] + sds[256 + j] + sds[512 + j] + sds[768 + j];
    }
}

// Stage-1 tree reduce: 25 psum rows per block, coalesced.
__global__ void k_red1(const float* __restrict__ psumA, const float* __restrict__ psumB,
                       float* __restrict__ psumA2, float* __restrict__ psumB2) {
    const int b = blockIdx.x, t = threadIdx.x;
    if (b < RA2) {
        const float* p = psumA + (size_t)b * 25 * 512;
        float s0 = 0.f, s1 = 0.f;
#pragma unroll 5
        for (int r = 0; r < 25; ++r) { s0 += p[r * 512 + t]; s1 += p[r * 512 + 256 + t]; }
        psumA2[(size_t)b * 512 + t] = s0;
        psumA2[(size_t)b * 512 + 256 + t] = s1;
    } else {
        const int bi = b - RA2;
        const float* p = psumB + (size_t)bi * 25 * 256;
        float s = 0.f;
#pragma unroll 5
        for (int r = 0; r < 25; ++r) s += p[r * 256 + t];
        psumB2[(size_t)bi * 256 + t] = s;
    }
}

// Final reduce -> s_j; c_j = scale_j * K_{j%2} @ s_j with K staged in LDS.
__global__ void k_cvec2(const float* __restrict__ rel,
                        const float* __restrict__ psumA2, const float* __restrict__ psumB2,
                        float* __restrict__ cvec) {
    const int j = blockIdx.x;        // 0..5: pos0,pos1,nh0,nh1,nt0,nt1
    const int tid = threadIdx.x;     // 256
    __shared__ float Kds[D * 129];
    __shared__ float red[256];
    __shared__ float sv[D];
    const float* Kp = rel + (size_t)(j & 1) * D * D;

    for (int e = tid; e < D * D / 4; e += 256) {
        const int row = e >> 5, col = (e & 31) * 4;
        const float4 v = *reinterpret_cast<const float4*>(Kp + (size_t)row * D + col);
        float* dst = Kds + row * 129 + col;
        dst[0] = v.x; dst[1] = v.y; dst[2] = v.z; dst[3] = v.w;
    }

    const int g = tid >> 7, i = tid & 127;
    float s = 0.f;
    if (j == 1 || j == 5) {
        const int plane = (j == 1) ? 0 : 1;
        for (int b = g; b < RB2; b += 2) s += psumB2[(size_t)b * 256 + plane * D + i];
    } else {
        const int plane = (j == 0) ? 0 : (j - 1);
        for (int b = g; b < RA2; b += 2) s += psumA2[(size_t)b * 512 + plane * D + i];
    }
    red[tid] = s;
    __syncthreads();
    if (tid < 128) sv[i] = red[i] + red[128 + i];
    __syncthreads();

    if (tid < 128) {
        const float scale = (j == 2 || j == 3) ? (float)S_NEG : 1.0f;
        float acc = 0.f;
#pragma unroll
        for (int k = 0; k < D; k += 4)
            acc += Kds[i * 129 + k] * sv[k] + Kds[i * 129 + k + 1] * sv[k + 1]
                 + Kds[i * 129 + k + 2] * sv[k + 2] + Kds[i * 129 + k + 3] * sv[k + 3];
        cvec[j * D + i] = acc * scale;
    }
}

// Lane-per-row dot products: no shuffles, coalesced SoA stores.
// PA[p*N_A+n] = emb_A[n].c_p (p=0..4); PB[n] = emb_B[n].c_5.
__global__ void __launch_bounds__(256, 4)
k_scan2(const float* __restrict__ embA, const float* __restrict__ embB,
        const float* __restrict__ cvec, float* __restrict__ PA,
        float* __restrict__ PB) {
    __shared__ float sc[5 * D];
    const int tid = threadIdx.x;

    if ((int)blockIdx.x < GA2) {
        for (int j = tid; j < 5 * D; j += 256) sc[j] = cvec[j];  // c0..c4
        __syncthreads();
        const int n = blockIdx.x * 256 + tid;
        const int nc = min(n, N_A - 1);
        const float4* row = reinterpret_cast<const float4*>(embA + (size_t)nc * D);
        float a0 = 0.f, a1 = 0.f, a2 = 0.f, a3 = 0.f, a4 = 0.f;
#pragma unroll 8
        for (int k = 0; k < 32; ++k) {
            const float4 x = row[k];
            a0 += dot4(x, *reinterpret_cast<const float4*>(sc + 0 * D + 4 * k));
            a1 += dot4(x, *reinterpret_cast<const float4*>(sc + 1 * D + 4 * k));
            a2 += dot4(x, *reinterpret_cast<const float4*>(sc + 2 * D + 4 * k));
            a3 += dot4(x, *reinterpret_cast<const float4*>(sc + 3 * D + 4 * k));
            a4 += dot4(x, *reinterpret_cast<const float4*>(sc + 4 * D + 4 * k));
        }
        if (n < N_A) {
            PA[0 * (size_t)N_A + n] = a0;
            PA[1 * (size_t)N_A + n] = a1;
            PA[2 * (size_t)N_A + n] = a2;
            PA[3 * (size_t)N_A + n] = a3;
            PA[4 * (size_t)N_A + n] = a4;
        }
    } else {
        for (int j = tid; j < D; j += 256) sc[j] = cvec[5 * D + j];  // c5
        __syncthreads();
        const int n = (blockIdx.x - GA2) * 256 + tid;
        const int nc = min(n, N_B - 1);
        const float4* row = reinterpret_cast<const float4*>(embB + (size_t)nc * D);
        float a0 = 0.f;
#pragma unroll 8
        for (int k = 0; k < 32; ++k) {
            const float4 x = row[k];
            a0 += dot4(x, *reinterpret_cast<const float4*>(sc + 4 * k));
        }
        if (n < N_B) PB[n] = a0;
    }
}

// Vectorized scatter from SoA planes: int4 index loads, float4 stores.
__global__ void k_scatter(const int* __restrict__ ei0, const int* __restrict__ ei1,
                          const int* __restrict__ nh0, const int* __restrict__ nh1,
                          const int* __restrict__ nt0, const int* __restrict__ nt1,
                          const float* __restrict__ PA, const float* __restrict__ PB,
                          float* __restrict__ out) {
    const int total4 = (2 * E_EDGES + 4 * ES) / 4;  // 825000
    const float* P0 = PA;
    const float* P1 = PA + (size_t)N_A;
    const float* P2 = PA + (size_t)2 * N_A;
    const float* P3 = PA + (size_t)3 * N_A;
    const float* P4 = PA + (size_t)4 * N_A;
    for (int t = blockIdx.x * blockDim.x + threadIdx.x; t < total4;
         t += gridDim.x * blockDim.x) {
        const int e = t * 4;
        float4 v;
        if (e < E_EDGES) {
            const int4 i4 = *reinterpret_cast<const int4*>(ei0 + e);
            v = make_float4(P0[i4.x], P0[i4.y], P0[i4.z], P0[i4.w]);
        } else if (e < 2 * E_EDGES) {
            const int4 i4 = *reinterpret_cast<const int4*>(ei1 + (e - E_EDGES));
            v = make_float4(P1[i4.x], P1[i4.y], P1[i4.z], P1[i4.w]);
        } else if (e < 2 * E_EDGES + ES) {
            const int4 i4 = *reinterpret_cast<const int4*>(nh0 + (e - 2 * E_EDGES));
            v = make_float4(P2[i4.x], P2[i4.y], P2[i4.z], P2[i4.w]);
        } else if (e < 2 * E_EDGES + 2 * ES) {
            const int4 i4 = *reinterpret_cast<const int4*>(nh1 + (e - 2 * E_EDGES - ES));
            v = make_float4(P3[i4.x], P3[i4.y], P3[i4.z], P3[i4.w]);
        } else if (e < 2 * E_EDGES + 3 * ES) {
            const int i = e - 2 * E_EDGES - 2 * ES;
            const float s = P4[nt0[(i >> 4) << 4]];
            v = make_float4(s, s, s, s);
        } else {
            const int i = e - 2 * E_EDGES - 3 * ES;
            const float s = PB[nt1[(i >> 4) << 4]];
            v = make_float4(s, s, s, s);
        }
        *reinterpret_cast<float4*>(out + e) = v;
    }
}

extern "C" void kernel_launch(void* const* d_in, const int* in_sizes, int n_in,
                              void* d_out, int out_size, void* d_ws, size_t ws_size,
                              hipStream_t stream) {
    const float* embA = (const float*)d_in[0];
    const float* embB = (const float*)d_in[1];
    const float* rel  = (const float*)d_in[2];
    const int* ei0 = (const int*)d_in[3];
    const int* ei1 = (const int*)d_in[4];
    const int* nh0 = (const int*)d_in[5];
    const int* nh1 = (const int*)d_in[6];
    const int* nt0 = (const int*)d_in[7];
    const int* nt1 = (const int*)d_in[8];
    float* out = (float*)d_out;

    uint32_t* partA = (uint32_t*)d_ws;                        // 76*HW
    uint32_t* partB = partA + (size_t)2 * ACH * HW;           // 34*HW
    float4* cwA = (float4*)(partB + (size_t)BCH * HW);        // N_A float4
    float2* cwB = (float2*)(cwA + N_A);                       // N_B float2
    float* psumA = (float*)(cwB + N_B);                       // GA1*512
    float* psumB = psumA + (size_t)GA1 * 512;                 // GB1*256
    float* psumA2 = psumB + (size_t)GB1 * 256;                // RA2*512
    float* psumB2 = psumA2 + (size_t)RA2 * 512;               // RB2*256
    float* cvec  = psumB2 + (size_t)RB2 * 256;                // 6*D
    float* PA    = cvec + 6 * D;                              // 5*N_A (SoA)
    float* PB    = PA + (size_t)5 * N_A;                      // N_B

    k_hist<<<2 * ACH + BCH, 512, 0, stream>>>(ei0, ei1, nh0, nh1, nt0, nt1, partA, partB);
    k_reduceC<<<(N_A + N_B + 255) / 256, 256, 0, stream>>>(partA, partB, cwA, cwB);
    k_scan1<<<GA1 + GB1, 256, 0, stream>>>(embA, embB, cwA, cwB, psumA, psumB);
    k_red1<<<RA2 + RB2, 256, 0, stream>>>(psumA, psumB, psumA2, psumB2);
    k_cvec2<<<6, 256, 0, stream>>>(rel, psumA2, psumB2, cvec);
    k_scan2<<<GA2 + GB2, 256, 0, stream>>>(embA, embB, cvec, PA, PB);
    k_scatter<<<2048, 256, 0, stream>>>(ei0, ei1, nh0, nh1, nt0, nt1, PA, PB, out);
}